// Round 3
// baseline (533.387 us; speedup 1.0000x reference)
//
#include <hip/hip_runtime.h>
#include <hip/hip_bf16.h>
#include <math.h>

// ---------------------------------------------------------------------------
// MultiHeadAttention: x[4,2048,1024] -> causal MHA (16 heads, d=64) -> out proj
// bf16 MFMA (16x16x32) everywhere; flash-style attention with paired q-tiles
// (uniform work per block), KB=64, V pre-transposed [bh][d][seq], DPP softmax,
// log2-domain exp, 2 barriers/trip (P is wave-private LDS).
// ---------------------------------------------------------------------------

typedef __bf16  bf16x8  __attribute__((ext_vector_type(8)));
typedef float   floatx4 __attribute__((ext_vector_type(4)));

__device__ __forceinline__ unsigned short f2bf(float f) {
    __hip_bfloat16 h = __float2bfloat16(f);
    return *reinterpret_cast<unsigned short*>(&h);
}

// DPP row_ror:N within 16-lane rows (full-rate VALU cross-lane)
template <int CTRL>
__device__ __forceinline__ float dppf(float x) {
    int i = __builtin_amdgcn_update_dpp(0, __builtin_bit_cast(int, x), CTRL, 0xF, 0xF, false);
    return __builtin_bit_cast(float, i);
}
__device__ __forceinline__ float rowmax16(float x) {
    x = fmaxf(x, dppf<0x128>(x));
    x = fmaxf(x, dppf<0x124>(x));
    x = fmaxf(x, dppf<0x122>(x));
    x = fmaxf(x, dppf<0x121>(x));
    return x;
}
__device__ __forceinline__ float rowsum16(float x) {
    x += dppf<0x128>(x);
    x += dppf<0x124>(x);
    x += dppf<0x122>(x);
    x += dppf<0x121>(x);
    return x;
}

// ---------------------------------------------------------------- convert x
__global__ void convert_x(const float* __restrict__ x, unsigned short* __restrict__ xb) {
    int i = (blockIdx.x * 256 + threadIdx.x) * 4;
    float4 v = *(const float4*)(x + i);
    ushort4 o;
    o.x = f2bf(v.x); o.y = f2bf(v.y); o.z = f2bf(v.z); o.w = f2bf(v.w);
    *(ushort4*)(xb + i) = o;
}

// ------------------------------------------------------- transpose weights
__global__ void transpose_w(const float* __restrict__ Wq, const float* __restrict__ Wk,
                            const float* __restrict__ Wv, const float* __restrict__ Wo,
                            unsigned short* __restrict__ WT, unsigned short* __restrict__ WoT) {
    __shared__ float tile[32][33];
    int mat = blockIdx.z;
    const float* src = (mat == 0) ? Wq : (mat == 1) ? Wk : (mat == 2) ? Wv : Wo;
    unsigned short* dst = (mat < 3) ? WT : WoT;
    int nbase = (mat < 3) ? mat * 1024 : 0;
    int kt = blockIdx.x * 32, nt = blockIdx.y * 32;
    int tx = threadIdx.x, ty = threadIdx.y;
    for (int j = 0; j < 32; j += 8)
        tile[ty + j][tx] = src[(kt + ty + j) * 1024 + nt + tx];
    __syncthreads();
    for (int j = 0; j < 32; j += 8) {
        int n = nt + ty + j;
        dst[(nbase + n) * 1024 + kt + tx] = f2bf(tile[tx][ty + j]);
    }
}

// ---------------------------------------------------------------- GEMM B^T
template <int EPI>
__global__ __launch_bounds__(256) void gemm_bt(const unsigned short* __restrict__ A,
                                               const unsigned short* __restrict__ B,
                                               unsigned short* __restrict__ Qo,
                                               unsigned short* __restrict__ Ko,
                                               unsigned short* __restrict__ Vo,
                                               const float* __restrict__ bias,
                                               float* __restrict__ Out) {
    constexpr int LDT = 72;
    __shared__ __align__(16) unsigned short As[128 * LDT];
    __shared__ __align__(16) unsigned short Bs[128 * LDT];

    int tid = threadIdx.x;
    int lane = tid & 63, w = tid >> 6;
    int wm = w >> 1, wn = w & 1;
    int lm = lane & 15, quad = lane >> 4;
    int m0 = blockIdx.y * 128, n0 = blockIdx.x * 128;

    floatx4 acc[4][4] = {};

    for (int kb = 0; kb < 1024; kb += 64) {
        __syncthreads();
        for (int p = 0; p < 4; ++p) {
            int id = p * 256 + tid;
            int row = id >> 3, cc = (id & 7) * 8;
            *(uint4*)&As[row * LDT + cc] = *(const uint4*)&A[(m0 + row) * 1024 + kb + cc];
            *(uint4*)&Bs[row * LDT + cc] = *(const uint4*)&B[(n0 + row) * 1024 + kb + cc];
        }
        __syncthreads();
        bf16x8 af[2][4], bf[2][4];
        for (int ks = 0; ks < 2; ++ks)
            for (int i = 0; i < 4; ++i) {
                af[ks][i] = *(const bf16x8*)&As[(wm * 64 + i * 16 + lm) * LDT + ks * 32 + quad * 8];
                bf[ks][i] = *(const bf16x8*)&Bs[(wn * 64 + i * 16 + lm) * LDT + ks * 32 + quad * 8];
            }
        for (int mi = 0; mi < 4; ++mi)
            for (int ni = 0; ni < 4; ++ni) {
                acc[mi][ni] = __builtin_amdgcn_mfma_f32_16x16x32_bf16(af[0][mi], bf[0][ni], acc[mi][ni], 0, 0, 0);
                acc[mi][ni] = __builtin_amdgcn_mfma_f32_16x16x32_bf16(af[1][mi], bf[1][ni], acc[mi][ni], 0, 0, 0);
            }
    }

    // C/D layout: col = lane&15, row = quad*4 + r
    for (int mi = 0; mi < 4; ++mi)
        for (int ni = 0; ni < 4; ++ni) {
            int gcol = n0 + wn * 64 + ni * 16 + lm;
            if constexpr (EPI == 0) {
                int which = gcol >> 10, hn = gcol & 1023;
                int h = hn >> 6, d = hn & 63;
                int grow0 = m0 + wm * 64 + mi * 16 + quad * 4;
                int bb = grow0 >> 11, s = grow0 & 2047;
                if (which == 2) {
                    ushort4 pk;
                    pk.x = f2bf(acc[mi][ni][0]); pk.y = f2bf(acc[mi][ni][1]);
                    pk.z = f2bf(acc[mi][ni][2]); pk.w = f2bf(acc[mi][ni][3]);
                    *(ushort4*)&Vo[((size_t)(bb * 16 + h) * 64 + d) * 2048 + s] = pk;
                } else {
                    unsigned short* dst = (which == 0) ? Qo : Ko;
                    for (int r = 0; r < 4; ++r)
                        dst[(((bb * 16 + h) * 2048) + s + r) * 64 + d] = f2bf(acc[mi][ni][r]);
                }
            } else {
                float bv = bias[gcol];
                for (int r = 0; r < 4; ++r) {
                    int grow = m0 + wm * 64 + mi * 16 + quad * 4 + r;
                    Out[(size_t)grow * 1024 + gcol] = acc[mi][ni][r] + bv;
                }
            }
        }
}

// ------------------------------------------------------------- attention
constexpr int LKS = 72, LVS = 72, LPS = 72;

// One 64-q-tile x 64-k-tile flash step for one wave (16 q rows).
// Pw is this wave's private P region: no barrier needed around it.
__device__ __forceinline__ void attn_tile_trip(
    bf16x8 aq0, bf16x8 aq1, floatx4 (&O)[4], float (&mrow)[4], float (&lrow)[4],
    const unsigned short* Ks, const unsigned short* Vts, unsigned short* Pw,
    int lm, int quad, bool diag, int qrel /* (qtile*64 + w*16) - kb */) {
    floatx4 s[4] = {};
    for (int n = 0; n < 4; ++n) {
        bf16x8 b0 = *(const bf16x8*)&Ks[(n * 16 + lm) * LKS + quad * 8];
        bf16x8 b1 = *(const bf16x8*)&Ks[(n * 16 + lm) * LKS + 32 + quad * 8];
        s[n] = __builtin_amdgcn_mfma_f32_16x16x32_bf16(aq0, b0, s[n], 0, 0, 0);
        s[n] = __builtin_amdgcn_mfma_f32_16x16x32_bf16(aq1, b1, s[n], 0, 0, 0);
    }
    const float scl = 0.125f * 1.44269504f;  // 1/sqrt(64) * log2(e)
    for (int r = 0; r < 4; ++r) {
        float v[4];
        if (diag) {
            int qr = qrel + quad * 4 + r;
            for (int n = 0; n < 4; ++n)
                v[n] = (n * 16 + lm <= qr) ? s[n][r] * scl : -INFINITY;
        } else {
            for (int n = 0; n < 4; ++n) v[n] = s[n][r] * scl;
        }
        float vm = fmaxf(fmaxf(v[0], v[1]), fmaxf(v[2], v[3]));
        vm = rowmax16(vm);
        float mnew = fmaxf(mrow[r], vm);
        float alpha = __builtin_amdgcn_exp2f(mrow[r] - mnew);
        float p[4], rs = 0.f;
        for (int n = 0; n < 4; ++n) {
            p[n] = __builtin_amdgcn_exp2f(v[n] - mnew);
            rs += p[n];
        }
        rs = rowsum16(rs);
        lrow[r] = lrow[r] * alpha + rs;
        mrow[r] = mnew;
        for (int dblk = 0; dblk < 4; ++dblk) O[dblk][r] *= alpha;
        for (int n = 0; n < 4; ++n)
            Pw[(quad * 4 + r) * LPS + n * 16 + lm] = f2bf(p[n]);
    }
    // wave-private LDS RAW: compiler inserts lgkmcnt wait, no barrier needed
    bf16x8 ap0 = *(const bf16x8*)&Pw[lm * LPS + quad * 8];
    bf16x8 ap1 = *(const bf16x8*)&Pw[lm * LPS + 32 + quad * 8];
    for (int dblk = 0; dblk < 4; ++dblk) {
        bf16x8 bv0 = *(const bf16x8*)&Vts[(dblk * 16 + lm) * LVS + quad * 8];
        bf16x8 bv1 = *(const bf16x8*)&Vts[(dblk * 16 + lm) * LVS + 32 + quad * 8];
        O[dblk] = __builtin_amdgcn_mfma_f32_16x16x32_bf16(ap0, bv0, O[dblk], 0, 0, 0);
        O[dblk] = __builtin_amdgcn_mfma_f32_16x16x32_bf16(ap1, bv1, O[dblk], 0, 0, 0);
    }
}

// grid (16 pairs, 64 bh), 256 thr (4 waves x 16 q-rows per tile).
// Block qp handles q-tiles qL=qp and qH=31-qp: uniform 33 tile-trips/block,
// shared K/V staging over k-blocks 0..31-qp (heaviest staging dispatched first).
__global__ __launch_bounds__(256, 4) void attn(const unsigned short* __restrict__ Q,
                                               const unsigned short* __restrict__ K,
                                               const unsigned short* __restrict__ Vt,
                                               unsigned short* __restrict__ ctx) {
    __shared__ __align__(16) unsigned short Ks[64 * LKS];
    __shared__ __align__(16) unsigned short Vts[64 * LVS];
    __shared__ __align__(16) unsigned short Ps[8 * 16 * LPS];  // 4 waves x 2 tiles

    int tid = threadIdx.x, lane = tid & 63, w = tid >> 6;
    int lm = lane & 15, quad = lane >> 4;
    int bh = blockIdx.y, qp = blockIdx.x;
    int qL = qp, qH = 31 - qp;
    int trips = 32 - qp;
    const unsigned short* Qg  = Q  + (size_t)bh * 2048 * 64;
    const unsigned short* Kg  = K  + (size_t)bh * 2048 * 64;
    const unsigned short* Vtg = Vt + (size_t)bh * 64 * 2048;

    int qrowL = qL * 64 + w * 16 + lm;
    int qrowH = qH * 64 + w * 16 + lm;
    bf16x8 aL0 = *(const bf16x8*)&Qg[qrowL * 64 + quad * 8];
    bf16x8 aL1 = *(const bf16x8*)&Qg[qrowL * 64 + 32 + quad * 8];
    bf16x8 aH0 = *(const bf16x8*)&Qg[qrowH * 64 + quad * 8];
    bf16x8 aH1 = *(const bf16x8*)&Qg[qrowH * 64 + 32 + quad * 8];

    floatx4 OL[4] = {}, OH[4] = {};
    float mL[4] = {-INFINITY, -INFINITY, -INFINITY, -INFINITY};
    float mH[4] = {-INFINITY, -INFINITY, -INFINITY, -INFINITY};
    float lL[4] = {0.f, 0.f, 0.f, 0.f};
    float lH[4] = {0.f, 0.f, 0.f, 0.f};

    unsigned short* PwH = Ps + w * 16 * LPS;
    unsigned short* PwL = Ps + (4 + w) * 16 * LPS;
    int r0 = tid >> 3, c0 = (tid & 7) * 8;

    for (int t = 0; t < trips; ++t) {
        int kb = t * 64;
        __syncthreads();  // protect staging vs prior trip's reads
        *(uint4*)&Ks[r0 * LKS + c0]         = *(const uint4*)&Kg[(kb + r0) * 64 + c0];
        *(uint4*)&Ks[(r0 + 32) * LKS + c0]  = *(const uint4*)&Kg[(kb + r0 + 32) * 64 + c0];
        *(uint4*)&Vts[r0 * LVS + c0]        = *(const uint4*)&Vtg[r0 * 2048 + kb + c0];
        *(uint4*)&Vts[(r0 + 32) * LVS + c0] = *(const uint4*)&Vtg[(r0 + 32) * 2048 + kb + c0];
        __syncthreads();

        attn_tile_trip(aH0, aH1, OH, mH, lH, Ks, Vts, PwH, lm, quad,
                       t == trips - 1, qH * 64 + w * 16 - kb);
        if (t <= qL)  // wave-uniform branch, no barriers inside
            attn_tile_trip(aL0, aL1, OL, mL, lL, Ks, Vts, PwL, lm, quad,
                           t == qL, qL * 64 + w * 16 - kb);
    }

    int b = bh >> 4, h = bh & 15;
    for (int r = 0; r < 4; ++r) {
        float invH = 1.0f / lH[r];
        float invL = 1.0f / lL[r];
        int sH = qH * 64 + w * 16 + quad * 4 + r;
        int sL = qL * 64 + w * 16 + quad * 4 + r;
        for (int dblk = 0; dblk < 4; ++dblk) {
            int d = dblk * 16 + lm;
            ctx[((size_t)(b * 2048 + sH)) * 1024 + h * 64 + d] = f2bf(OH[dblk][r] * invH);
            ctx[((size_t)(b * 2048 + sL)) * 1024 + h * 64 + d] = f2bf(OL[dblk][r] * invL);
        }
    }
}

// ---------------------------------------------------------------- launch
extern "C" void kernel_launch(void* const* d_in, const int* in_sizes, int n_in,
                              void* d_out, int out_size, void* d_ws, size_t ws_size,
                              hipStream_t stream) {
    const float* x   = (const float*)d_in[0];
    const float* Wq  = (const float*)d_in[1];
    const float* Wk  = (const float*)d_in[2];
    const float* Wv  = (const float*)d_in[3];
    const float* Wo  = (const float*)d_in[4];
    const float* bo  = (const float*)d_in[5];
    float* out = (float*)d_out;

    char* ws = (char*)d_ws;
    unsigned short* xb  = (unsigned short*)(ws);               // 16 MB
    unsigned short* WT  = (unsigned short*)(ws + 16777216);    // 6 MB
    unsigned short* WoT = (unsigned short*)(ws + 23068672);    // 2 MB
    unsigned short* Qb  = (unsigned short*)(ws + 25165824);    // 16 MB
    unsigned short* Kb  = (unsigned short*)(ws + 41943040);    // 16 MB
    unsigned short* Vtb = (unsigned short*)(ws + 58720256);    // 16 MB (transposed)
    unsigned short* ctx = (unsigned short*)(ws + 75497472);    // 16 MB

    convert_x<<<8192, 256, 0, stream>>>(x, xb);
    transpose_w<<<dim3(32, 32, 4), dim3(32, 8), 0, stream>>>(Wq, Wk, Wv, Wo, WT, WoT);
    gemm_bt<0><<<dim3(24, 64), 256, 0, stream>>>(xb, WT, Qb, Kb, Vtb, nullptr, nullptr);
    attn<<<dim3(16, 64), 256, 0, stream>>>(Qb, Kb, Vtb, ctx);
    gemm_bt<1><<<dim3(8, 64), 256, 0, stream>>>(ctx, WoT, nullptr, nullptr, nullptr, bo, out);
}

// Round 4
// 456.406 us; speedup vs baseline: 1.1687x; 1.1687x over previous
//
#include <hip/hip_runtime.h>
#include <hip/hip_bf16.h>
#include <math.h>

// ---------------------------------------------------------------------------
// MultiHeadAttention: x[4,2048,1024] -> causal MHA (16 heads, d=64) -> out proj
// bf16 MFMA (16x16x32) everywhere.
// Attention: barrier-free flash — K/V^T frags loaded direct from global
// (L1/L2-resident tiles), LDS only for wave-private P, LPT dispatch order.
// GEMMs: m97 pattern — global_load_lds width-16 staging, stride-64 LDS.
// ---------------------------------------------------------------------------

typedef __bf16  bf16x8  __attribute__((ext_vector_type(8)));
typedef float   floatx4 __attribute__((ext_vector_type(4)));

__device__ __forceinline__ unsigned short f2bf(float f) {
    __hip_bfloat16 h = __float2bfloat16(f);
    return *reinterpret_cast<unsigned short*>(&h);
}

// async global->LDS, 16 B per lane; LDS dest = wave-uniform base + lane*16
__device__ __forceinline__ void gll16(const unsigned short* g, unsigned short* l) {
    __builtin_amdgcn_global_load_lds(
        (const __attribute__((address_space(1))) unsigned int*)g,
        (__attribute__((address_space(3))) unsigned int*)l, 16, 0, 0);
}

// DPP row_ror:N within 16-lane rows (full-rate VALU cross-lane)
template <int CTRL>
__device__ __forceinline__ float dppf(float x) {
    int i = __builtin_amdgcn_update_dpp(0, __builtin_bit_cast(int, x), CTRL, 0xF, 0xF, false);
    return __builtin_bit_cast(float, i);
}
__device__ __forceinline__ float rowmax16(float x) {
    x = fmaxf(x, dppf<0x128>(x));
    x = fmaxf(x, dppf<0x124>(x));
    x = fmaxf(x, dppf<0x122>(x));
    x = fmaxf(x, dppf<0x121>(x));
    return x;
}
__device__ __forceinline__ float rowsum16(float x) {
    x += dppf<0x128>(x);
    x += dppf<0x124>(x);
    x += dppf<0x122>(x);
    x += dppf<0x121>(x);
    return x;
}

// ---------------------------------------------------------------- convert x
__global__ void convert_x(const float* __restrict__ x, unsigned short* __restrict__ xb) {
    int i = (blockIdx.x * 256 + threadIdx.x) * 4;
    float4 v = *(const float4*)(x + i);
    ushort4 o;
    o.x = f2bf(v.x); o.y = f2bf(v.y); o.z = f2bf(v.z); o.w = f2bf(v.w);
    *(ushort4*)(xb + i) = o;
}

// ------------------------------------------------------- transpose weights
__global__ void transpose_w(const float* __restrict__ Wq, const float* __restrict__ Wk,
                            const float* __restrict__ Wv, const float* __restrict__ Wo,
                            unsigned short* __restrict__ WT, unsigned short* __restrict__ WoT) {
    __shared__ float tile[32][33];
    int mat = blockIdx.z;
    const float* src = (mat == 0) ? Wq : (mat == 1) ? Wk : (mat == 2) ? Wv : Wo;
    unsigned short* dst = (mat < 3) ? WT : WoT;
    int nbase = (mat < 3) ? mat * 1024 : 0;
    int kt = blockIdx.x * 32, nt = blockIdx.y * 32;
    int tx = threadIdx.x, ty = threadIdx.y;
    for (int j = 0; j < 32; j += 8)
        tile[ty + j][tx] = src[(kt + ty + j) * 1024 + nt + tx];
    __syncthreads();
    for (int j = 0; j < 32; j += 8) {
        int n = nt + ty + j;
        dst[(nbase + n) * 1024 + kt + tx] = f2bf(tile[tx][ty + j]);
    }
}

// ---------------------------------------------------------------- GEMM B^T
// C[M,N] = A[M,1024] @ B^T (B stored [N][1024]). 128x128 tile, BK=64.
// m97-style staging: global_load_lds dwordx4, unpadded stride-64 LDS.
// EPI 0: scatter Q,K -> [bh][seq][64]; V -> transposed [bh][64][2048].
// EPI 1: +bias, fp32 out.
template <int EPI>
__global__ __launch_bounds__(256) void gemm_bt(const unsigned short* __restrict__ A,
                                               const unsigned short* __restrict__ B,
                                               unsigned short* __restrict__ Qo,
                                               unsigned short* __restrict__ Ko,
                                               unsigned short* __restrict__ Vo,
                                               const float* __restrict__ bias,
                                               float* __restrict__ Out) {
    __shared__ __align__(16) unsigned short As[128 * 64];
    __shared__ __align__(16) unsigned short Bs[128 * 64];

    int tid = threadIdx.x;
    int lane = tid & 63, w = tid >> 6;
    int wm = w >> 1, wn = w & 1;
    int lm = lane & 15, quad = lane >> 4;
    int m0 = blockIdx.y * 128, n0 = blockIdx.x * 128;

    floatx4 acc[4][4] = {};

    for (int kb = 0; kb < 1024; kb += 64) {
        __syncthreads();
        for (int p = 0; p < 4; ++p) {
            int id = p * 256 + tid;
            int row = id >> 3, cc = (id & 7) * 8;
            int lbase = (p * 256 + w * 64) * 8;  // wave-uniform; HW adds lane*16B
            gll16(&A[(m0 + row) * 1024 + kb + cc], &As[lbase]);
            gll16(&B[(n0 + row) * 1024 + kb + cc], &Bs[lbase]);
        }
        __syncthreads();
        bf16x8 af[2][4], bf[2][4];
        for (int ks = 0; ks < 2; ++ks)
            for (int i = 0; i < 4; ++i) {
                af[ks][i] = *(const bf16x8*)&As[(wm * 64 + i * 16 + lm) * 64 + ks * 32 + quad * 8];
                bf[ks][i] = *(const bf16x8*)&Bs[(wn * 64 + i * 16 + lm) * 64 + ks * 32 + quad * 8];
            }
        for (int mi = 0; mi < 4; ++mi)
            for (int ni = 0; ni < 4; ++ni) {
                acc[mi][ni] = __builtin_amdgcn_mfma_f32_16x16x32_bf16(af[0][mi], bf[0][ni], acc[mi][ni], 0, 0, 0);
                acc[mi][ni] = __builtin_amdgcn_mfma_f32_16x16x32_bf16(af[1][mi], bf[1][ni], acc[mi][ni], 0, 0, 0);
            }
    }

    // C/D layout: col = lane&15, row = quad*4 + r
    for (int mi = 0; mi < 4; ++mi)
        for (int ni = 0; ni < 4; ++ni) {
            int gcol = n0 + wn * 64 + ni * 16 + lm;
            if constexpr (EPI == 0) {
                int which = gcol >> 10, hn = gcol & 1023;
                int h = hn >> 6, d = hn & 63;
                int grow0 = m0 + wm * 64 + mi * 16 + quad * 4;
                int bb = grow0 >> 11, s = grow0 & 2047;
                if (which == 2) {
                    ushort4 pk;
                    pk.x = f2bf(acc[mi][ni][0]); pk.y = f2bf(acc[mi][ni][1]);
                    pk.z = f2bf(acc[mi][ni][2]); pk.w = f2bf(acc[mi][ni][3]);
                    *(ushort4*)&Vo[((size_t)(bb * 16 + h) * 64 + d) * 2048 + s] = pk;
                } else {
                    unsigned short* dst = (which == 0) ? Qo : Ko;
                    for (int r = 0; r < 4; ++r)
                        dst[(((bb * 16 + h) * 2048) + s + r) * 64 + d] = f2bf(acc[mi][ni][r]);
                }
            } else {
                float bv = bias[gcol];
                for (int r = 0; r < 4; ++r) {
                    int grow = m0 + wm * 64 + mi * 16 + quad * 4 + r;
                    Out[(size_t)grow * 1024 + gcol] = acc[mi][ni][r] + bv;
                }
            }
        }
}

// ------------------------------------------------------------- attention
// Barrier-free flash. Flat grid 2048 = (qt heavy-first) x 64 bh.
// 256 thr = 4 waves; wave w owns q rows qt*64 + w*16 .. +15 (one A-frag).
// K/V^T frags read DIRECT from global (no staging, no __syncthreads).
// LDS: wave-private P only.
__global__ __launch_bounds__(256) void attn(const unsigned short* __restrict__ Q,
                                            const unsigned short* __restrict__ K,
                                            const unsigned short* __restrict__ Vt,
                                            unsigned short* __restrict__ ctx) {
    constexpr int LPS = 72;
    __shared__ __align__(16) unsigned short Ps[4 * 16 * LPS];

    int tid = threadIdx.x, lane = tid & 63, w = tid >> 6;
    int lm = lane & 15, quad = lane >> 4;
    int blk = blockIdx.x;
    int bh = blk & 63;
    int qt = 31 - (blk >> 6);   // LPT: heaviest q-tiles dispatch first
    const unsigned short* Qg  = Q  + (size_t)bh * 2048 * 64;
    const unsigned short* Kg  = K  + (size_t)bh * 2048 * 64;
    const unsigned short* Vtg = Vt + (size_t)bh * 64 * 2048;

    int qrow = qt * 64 + w * 16 + lm;  // A-frag row (m = lane&15)
    bf16x8 aq0 = *(const bf16x8*)&Qg[qrow * 64 + quad * 8];
    bf16x8 aq1 = *(const bf16x8*)&Qg[qrow * 64 + 32 + quad * 8];

    floatx4 O[4] = {};
    float mrow[4] = {-INFINITY, -INFINITY, -INFINITY, -INFINITY};
    float lrow[4] = {0.f, 0.f, 0.f, 0.f};
    const float scl = 0.125f * 1.44269504f;  // 1/sqrt(64) * log2(e)
    int trips = qt + 1;

    unsigned short* Pw = Ps + w * 16 * LPS;

    for (int t = 0; t < trips; ++t) {
        int kb = t * 64;

        // S = Q K^T : B-frags of K direct from global ([seq][64] layout)
        floatx4 s[4] = {};
        for (int n = 0; n < 4; ++n) {
            const unsigned short* kr = &Kg[(kb + n * 16 + lm) * 64];
            bf16x8 b0 = *(const bf16x8*)&kr[quad * 8];
            bf16x8 b1 = *(const bf16x8*)&kr[32 + quad * 8];
            s[n] = __builtin_amdgcn_mfma_f32_16x16x32_bf16(aq0, b0, s[n], 0, 0, 0);
            s[n] = __builtin_amdgcn_mfma_f32_16x16x32_bf16(aq1, b1, s[n], 0, 0, 0);
        }

        // online softmax (log2 domain), DPP reductions over 16-lane rows
        bool diag = (t == trips - 1);  // wave-uniform
        for (int r = 0; r < 4; ++r) {
            float v[4];
            if (diag) {
                int qr = w * 16 + quad * 4 + r;  // q - qt*64; kb == qt*64 here
                for (int n = 0; n < 4; ++n)
                    v[n] = (n * 16 + lm <= qr) ? s[n][r] * scl : -INFINITY;
            } else {
                for (int n = 0; n < 4; ++n) v[n] = s[n][r] * scl;
            }
            float vm = fmaxf(fmaxf(v[0], v[1]), fmaxf(v[2], v[3]));
            vm = rowmax16(vm);
            float mnew = fmaxf(mrow[r], vm);
            float alpha = __builtin_amdgcn_exp2f(mrow[r] - mnew);
            float p[4], rs = 0.f;
            for (int n = 0; n < 4; ++n) {
                p[n] = __builtin_amdgcn_exp2f(v[n] - mnew);
                rs += p[n];
            }
            rs = rowsum16(rs);
            lrow[r] = lrow[r] * alpha + rs;
            mrow[r] = mnew;
            for (int dblk = 0; dblk < 4; ++dblk) O[dblk][r] *= alpha;
            for (int n = 0; n < 4; ++n)
                Pw[(quad * 4 + r) * LPS + n * 16 + lm] = f2bf(p[n]);
        }

        // O += P V : P from wave-private LDS (lgkmcnt auto-wait), V^T direct
        bf16x8 ap0 = *(const bf16x8*)&Pw[lm * LPS + quad * 8];
        bf16x8 ap1 = *(const bf16x8*)&Pw[lm * LPS + 32 + quad * 8];
        for (int dblk = 0; dblk < 4; ++dblk) {
            const unsigned short* vr = &Vtg[(dblk * 16 + lm) * 2048 + kb];
            bf16x8 bv0 = *(const bf16x8*)&vr[quad * 8];
            bf16x8 bv1 = *(const bf16x8*)&vr[32 + quad * 8];
            O[dblk] = __builtin_amdgcn_mfma_f32_16x16x32_bf16(ap0, bv0, O[dblk], 0, 0, 0);
            O[dblk] = __builtin_amdgcn_mfma_f32_16x16x32_bf16(ap1, bv1, O[dblk], 0, 0, 0);
        }
    }

    int b = bh >> 4, h = bh & 15;
    for (int r = 0; r < 4; ++r) {
        int q = qt * 64 + w * 16 + quad * 4 + r;
        float inv = 1.0f / lrow[r];
        for (int dblk = 0; dblk < 4; ++dblk) {
            int d = dblk * 16 + lm;
            ctx[((size_t)(b * 2048 + q)) * 1024 + h * 64 + d] = f2bf(O[dblk][r] * inv);
        }
    }
}

// ---------------------------------------------------------------- launch
extern "C" void kernel_launch(void* const* d_in, const int* in_sizes, int n_in,
                              void* d_out, int out_size, void* d_ws, size_t ws_size,
                              hipStream_t stream) {
    const float* x   = (const float*)d_in[0];
    const float* Wq  = (const float*)d_in[1];
    const float* Wk  = (const float*)d_in[2];
    const float* Wv  = (const float*)d_in[3];
    const float* Wo  = (const float*)d_in[4];
    const float* bo  = (const float*)d_in[5];
    float* out = (float*)d_out;

    char* ws = (char*)d_ws;
    unsigned short* xb  = (unsigned short*)(ws);               // 16 MB
    unsigned short* WT  = (unsigned short*)(ws + 16777216);    // 6 MB
    unsigned short* WoT = (unsigned short*)(ws + 23068672);    // 2 MB
    unsigned short* Qb  = (unsigned short*)(ws + 25165824);    // 16 MB
    unsigned short* Kb  = (unsigned short*)(ws + 41943040);    // 16 MB
    unsigned short* Vtb = (unsigned short*)(ws + 58720256);    // 16 MB (transposed)
    unsigned short* ctx = (unsigned short*)(ws + 75497472);    // 16 MB

    convert_x<<<8192, 256, 0, stream>>>(x, xb);
    transpose_w<<<dim3(32, 32, 4), dim3(32, 8), 0, stream>>>(Wq, Wk, Wv, Wo, WT, WoT);
    gemm_bt<0><<<dim3(24, 64), 256, 0, stream>>>(xb, WT, Qb, Kb, Vtb, nullptr, nullptr);
    attn<<<2048, 256, 0, stream>>>(Qb, Kb, Vtb, ctx);
    gemm_bt<1><<<dim3(8, 64), 256, 0, stream>>>(ctx, WoT, nullptr, nullptr, nullptr, bo, out);
}

// Round 5
// 296.271 us; speedup vs baseline: 1.8003x; 1.5405x over previous
//
#include <hip/hip_runtime.h>
#include <hip/hip_bf16.h>
#include <math.h>

// ---------------------------------------------------------------------------
// MultiHeadAttention: x[4,2048,1024] -> causal MHA (16 heads, d=64) -> out proj
// bf16 MFMA (16x16x32) everywhere.
// Attention: flash with DOUBLE-BUFFERED cooperative LDS staging (prefetch next
// K/V tile to VGPR at trip start, ds_write after compute, 1 barrier/trip),
// LPT flat grid (heavy q-tiles first), wave-private P, DPP softmax, exp2.
// GEMMs: m97 pattern — global_load_lds width-16 staging, stride-64 LDS.
// ---------------------------------------------------------------------------

typedef __bf16  bf16x8  __attribute__((ext_vector_type(8)));
typedef float   floatx4 __attribute__((ext_vector_type(4)));

__device__ __forceinline__ unsigned short f2bf(float f) {
    __hip_bfloat16 h = __float2bfloat16(f);
    return *reinterpret_cast<unsigned short*>(&h);
}

// async global->LDS, 16 B per lane; LDS dest = wave-uniform base + lane*16
__device__ __forceinline__ void gll16(const unsigned short* g, unsigned short* l) {
    __builtin_amdgcn_global_load_lds(
        (const __attribute__((address_space(1))) unsigned int*)g,
        (__attribute__((address_space(3))) unsigned int*)l, 16, 0, 0);
}

// DPP row_ror:N within 16-lane rows (full-rate VALU cross-lane)
template <int CTRL>
__device__ __forceinline__ float dppf(float x) {
    int i = __builtin_amdgcn_update_dpp(0, __builtin_bit_cast(int, x), CTRL, 0xF, 0xF, false);
    return __builtin_bit_cast(float, i);
}
__device__ __forceinline__ float rowmax16(float x) {
    x = fmaxf(x, dppf<0x128>(x));
    x = fmaxf(x, dppf<0x124>(x));
    x = fmaxf(x, dppf<0x122>(x));
    x = fmaxf(x, dppf<0x121>(x));
    return x;
}
__device__ __forceinline__ float rowsum16(float x) {
    x += dppf<0x128>(x);
    x += dppf<0x124>(x);
    x += dppf<0x122>(x);
    x += dppf<0x121>(x);
    return x;
}

// ---------------------------------------------------------------- convert x
__global__ void convert_x(const float* __restrict__ x, unsigned short* __restrict__ xb) {
    int i = (blockIdx.x * 256 + threadIdx.x) * 4;
    float4 v = *(const float4*)(x + i);
    ushort4 o;
    o.x = f2bf(v.x); o.y = f2bf(v.y); o.z = f2bf(v.z); o.w = f2bf(v.w);
    *(ushort4*)(xb + i) = o;
}

// ------------------------------------------------------- transpose weights
__global__ void transpose_w(const float* __restrict__ Wq, const float* __restrict__ Wk,
                            const float* __restrict__ Wv, const float* __restrict__ Wo,
                            unsigned short* __restrict__ WT, unsigned short* __restrict__ WoT) {
    __shared__ float tile[32][33];
    int mat = blockIdx.z;
    const float* src = (mat == 0) ? Wq : (mat == 1) ? Wk : (mat == 2) ? Wv : Wo;
    unsigned short* dst = (mat < 3) ? WT : WoT;
    int nbase = (mat < 3) ? mat * 1024 : 0;
    int kt = blockIdx.x * 32, nt = blockIdx.y * 32;
    int tx = threadIdx.x, ty = threadIdx.y;
    for (int j = 0; j < 32; j += 8)
        tile[ty + j][tx] = src[(kt + ty + j) * 1024 + nt + tx];
    __syncthreads();
    for (int j = 0; j < 32; j += 8) {
        int n = nt + ty + j;
        dst[(nbase + n) * 1024 + kt + tx] = f2bf(tile[tx][ty + j]);
    }
}

// ---------------------------------------------------------------- GEMM B^T
// C[M,N] = A[M,1024] @ B^T (B stored [N][1024]). 128x128 tile, BK=64.
// m97-style staging: global_load_lds dwordx4, unpadded stride-64 LDS.
template <int EPI>
__global__ __launch_bounds__(256) void gemm_bt(const unsigned short* __restrict__ A,
                                               const unsigned short* __restrict__ B,
                                               unsigned short* __restrict__ Qo,
                                               unsigned short* __restrict__ Ko,
                                               unsigned short* __restrict__ Vo,
                                               const float* __restrict__ bias,
                                               float* __restrict__ Out) {
    __shared__ __align__(16) unsigned short As[128 * 64];
    __shared__ __align__(16) unsigned short Bs[128 * 64];

    int tid = threadIdx.x;
    int lane = tid & 63, w = tid >> 6;
    int wm = w >> 1, wn = w & 1;
    int lm = lane & 15, quad = lane >> 4;
    int m0 = blockIdx.y * 128, n0 = blockIdx.x * 128;

    floatx4 acc[4][4] = {};

    for (int kb = 0; kb < 1024; kb += 64) {
        __syncthreads();
        for (int p = 0; p < 4; ++p) {
            int id = p * 256 + tid;
            int row = id >> 3, cc = (id & 7) * 8;
            int lbase = (p * 256 + w * 64) * 8;  // wave-uniform; HW adds lane*16B
            gll16(&A[(m0 + row) * 1024 + kb + cc], &As[lbase]);
            gll16(&B[(n0 + row) * 1024 + kb + cc], &Bs[lbase]);
        }
        __syncthreads();
        bf16x8 af[2][4], bf[2][4];
        for (int ks = 0; ks < 2; ++ks)
            for (int i = 0; i < 4; ++i) {
                af[ks][i] = *(const bf16x8*)&As[(wm * 64 + i * 16 + lm) * 64 + ks * 32 + quad * 8];
                bf[ks][i] = *(const bf16x8*)&Bs[(wn * 64 + i * 16 + lm) * 64 + ks * 32 + quad * 8];
            }
        for (int mi = 0; mi < 4; ++mi)
            for (int ni = 0; ni < 4; ++ni) {
                acc[mi][ni] = __builtin_amdgcn_mfma_f32_16x16x32_bf16(af[0][mi], bf[0][ni], acc[mi][ni], 0, 0, 0);
                acc[mi][ni] = __builtin_amdgcn_mfma_f32_16x16x32_bf16(af[1][mi], bf[1][ni], acc[mi][ni], 0, 0, 0);
            }
    }

    // C/D layout: col = lane&15, row = quad*4 + r
    for (int mi = 0; mi < 4; ++mi)
        for (int ni = 0; ni < 4; ++ni) {
            int gcol = n0 + wn * 64 + ni * 16 + lm;
            if constexpr (EPI == 0) {
                int which = gcol >> 10, hn = gcol & 1023;
                int h = hn >> 6, d = hn & 63;
                int grow0 = m0 + wm * 64 + mi * 16 + quad * 4;
                int bb = grow0 >> 11, s = grow0 & 2047;
                if (which == 2) {
                    ushort4 pk;
                    pk.x = f2bf(acc[mi][ni][0]); pk.y = f2bf(acc[mi][ni][1]);
                    pk.z = f2bf(acc[mi][ni][2]); pk.w = f2bf(acc[mi][ni][3]);
                    *(ushort4*)&Vo[((size_t)(bb * 16 + h) * 64 + d) * 2048 + s] = pk;
                } else {
                    unsigned short* dst = (which == 0) ? Qo : Ko;
                    for (int r = 0; r < 4; ++r)
                        dst[(((bb * 16 + h) * 2048) + s + r) * 64 + d] = f2bf(acc[mi][ni][r]);
                }
            } else {
                float bv = bias[gcol];
                for (int r = 0; r < 4; ++r) {
                    int grow = m0 + wm * 64 + mi * 16 + quad * 4 + r;
                    Out[(size_t)grow * 1024 + gcol] = acc[mi][ni][r] + bv;
                }
            }
        }
}

// ------------------------------------------------------------- attention
// Flat grid 2048 = (qt heavy-first) x 64 bh. 4 waves x 16 q-rows. KB=64.
// Double-buffered staging: prefetch next K/V tile to VGPR at trip start,
// compute current tile, ds_write prefetch to other buffer, 1 barrier/trip.
__global__ __launch_bounds__(256) void attn(const unsigned short* __restrict__ Q,
                                            const unsigned short* __restrict__ K,
                                            const unsigned short* __restrict__ Vt,
                                            unsigned short* __restrict__ ctx) {
    constexpr int LKS = 72, LPS = 72;
    __shared__ __align__(16) unsigned short Ks[2][64 * LKS];
    __shared__ __align__(16) unsigned short Vts[2][64 * LKS];
    __shared__ __align__(16) unsigned short Ps[4 * 16 * LPS];

    int tid = threadIdx.x, lane = tid & 63, w = tid >> 6;
    int lm = lane & 15, quad = lane >> 4;
    int blk = blockIdx.x;
    int bh = blk & 63;
    int qt = 31 - (blk >> 6);   // LPT: heaviest q-tiles dispatch first
    int trips = qt + 1;
    const unsigned short* Qg  = Q  + (size_t)bh * 2048 * 64;
    const unsigned short* Kg  = K  + (size_t)bh * 2048 * 64;
    const unsigned short* Vtg = Vt + (size_t)bh * 64 * 2048;

    int qrow = qt * 64 + w * 16 + lm;  // A-frag row (m = lane&15)
    bf16x8 aq0 = *(const bf16x8*)&Qg[qrow * 64 + quad * 8];
    bf16x8 aq1 = *(const bf16x8*)&Qg[qrow * 64 + 32 + quad * 8];

    floatx4 O[4] = {};
    float mrow[4] = {-INFINITY, -INFINITY, -INFINITY, -INFINITY};
    float lrow[4] = {0.f, 0.f, 0.f, 0.f};
    const float scl = 0.125f * 1.44269504f;  // 1/sqrt(64) * log2(e)

    unsigned short* Pw = Ps + w * 16 * LPS;
    int r0 = tid >> 3, c0 = (tid & 7) * 8;  // staging coords

    // prologue: stage tile 0 into buffer 0
    {
        uint4 k0 = *(const uint4*)&Kg[r0 * 64 + c0];
        uint4 k1 = *(const uint4*)&Kg[(r0 + 32) * 64 + c0];
        uint4 v0 = *(const uint4*)&Vtg[r0 * 2048 + c0];
        uint4 v1 = *(const uint4*)&Vtg[(r0 + 32) * 2048 + c0];
        *(uint4*)&Ks[0][r0 * LKS + c0]        = k0;
        *(uint4*)&Ks[0][(r0 + 32) * LKS + c0] = k1;
        *(uint4*)&Vts[0][r0 * LKS + c0]        = v0;
        *(uint4*)&Vts[0][(r0 + 32) * LKS + c0] = v1;
    }
    __syncthreads();

    for (int t = 0; t < trips; ++t) {
        int cur = t & 1, nxt = cur ^ 1;
        bool pre = (t + 1 < trips);
        uint4 pk0, pk1, pv0, pv1;
        if (pre) {  // issue next tile's loads NOW; they complete under compute
            int kb2 = (t + 1) * 64;
            pk0 = *(const uint4*)&Kg[(kb2 + r0) * 64 + c0];
            pk1 = *(const uint4*)&Kg[(kb2 + r0 + 32) * 64 + c0];
            pv0 = *(const uint4*)&Vtg[r0 * 2048 + kb2 + c0];
            pv1 = *(const uint4*)&Vtg[(r0 + 32) * 2048 + kb2 + c0];
        }

        // S = Q K^T from LDS
        const unsigned short* Kc = Ks[cur];
        const unsigned short* Vc = Vts[cur];
        floatx4 s[4] = {};
        for (int n = 0; n < 4; ++n) {
            bf16x8 b0 = *(const bf16x8*)&Kc[(n * 16 + lm) * LKS + quad * 8];
            bf16x8 b1 = *(const bf16x8*)&Kc[(n * 16 + lm) * LKS + 32 + quad * 8];
            s[n] = __builtin_amdgcn_mfma_f32_16x16x32_bf16(aq0, b0, s[n], 0, 0, 0);
            s[n] = __builtin_amdgcn_mfma_f32_16x16x32_bf16(aq1, b1, s[n], 0, 0, 0);
        }

        // online softmax (log2 domain), DPP reductions
        bool diag = (t == trips - 1);  // wave-uniform
        for (int r = 0; r < 4; ++r) {
            float v[4];
            if (diag) {
                int qr = w * 16 + quad * 4 + r;  // q - kb on the diagonal tile
                for (int n = 0; n < 4; ++n)
                    v[n] = (n * 16 + lm <= qr) ? s[n][r] * scl : -INFINITY;
            } else {
                for (int n = 0; n < 4; ++n) v[n] = s[n][r] * scl;
            }
            float vm = fmaxf(fmaxf(v[0], v[1]), fmaxf(v[2], v[3]));
            vm = rowmax16(vm);
            float mnew = fmaxf(mrow[r], vm);
            float alpha = __builtin_amdgcn_exp2f(mrow[r] - mnew);
            float p[4], rs = 0.f;
            for (int n = 0; n < 4; ++n) {
                p[n] = __builtin_amdgcn_exp2f(v[n] - mnew);
                rs += p[n];
            }
            rs = rowsum16(rs);
            lrow[r] = lrow[r] * alpha + rs;
            mrow[r] = mnew;
            for (int dblk = 0; dblk < 4; ++dblk) O[dblk][r] *= alpha;
            for (int n = 0; n < 4; ++n)
                Pw[(quad * 4 + r) * LPS + n * 16 + lm] = f2bf(p[n]);
        }

        // O += P V (P wave-private: lgkmcnt auto-wait, no barrier)
        bf16x8 ap0 = *(const bf16x8*)&Pw[lm * LPS + quad * 8];
        bf16x8 ap1 = *(const bf16x8*)&Pw[lm * LPS + 32 + quad * 8];
        for (int dblk = 0; dblk < 4; ++dblk) {
            bf16x8 bv0 = *(const bf16x8*)&Vc[(dblk * 16 + lm) * LKS + quad * 8];
            bf16x8 bv1 = *(const bf16x8*)&Vc[(dblk * 16 + lm) * LKS + 32 + quad * 8];
            O[dblk] = __builtin_amdgcn_mfma_f32_16x16x32_bf16(ap0, bv0, O[dblk], 0, 0, 0);
            O[dblk] = __builtin_amdgcn_mfma_f32_16x16x32_bf16(ap1, bv1, O[dblk], 0, 0, 0);
        }

        if (pre) {  // loads completed under compute; write into other buffer
            *(uint4*)&Ks[nxt][r0 * LKS + c0]        = pk0;
            *(uint4*)&Ks[nxt][(r0 + 32) * LKS + c0] = pk1;
            *(uint4*)&Vts[nxt][r0 * LKS + c0]        = pv0;
            *(uint4*)&Vts[nxt][(r0 + 32) * LKS + c0] = pv1;
        }
        __syncthreads();
    }

    int b = bh >> 4, h = bh & 15;
    for (int r = 0; r < 4; ++r) {
        int q = qt * 64 + w * 16 + quad * 4 + r;
        float inv = 1.0f / lrow[r];
        for (int dblk = 0; dblk < 4; ++dblk) {
            int d = dblk * 16 + lm;
            ctx[((size_t)(b * 2048 + q)) * 1024 + h * 64 + d] = f2bf(O[dblk][r] * inv);
        }
    }
}

// ---------------------------------------------------------------- launch
extern "C" void kernel_launch(void* const* d_in, const int* in_sizes, int n_in,
                              void* d_out, int out_size, void* d_ws, size_t ws_size,
                              hipStream_t stream) {
    const float* x   = (const float*)d_in[0];
    const float* Wq  = (const float*)d_in[1];
    const float* Wk  = (const float*)d_in[2];
    const float* Wv  = (const float*)d_in[3];
    const float* Wo  = (const float*)d_in[4];
    const float* bo  = (const float*)d_in[5];
    float* out = (float*)d_out;

    char* ws = (char*)d_ws;
    unsigned short* xb  = (unsigned short*)(ws);               // 16 MB
    unsigned short* WT  = (unsigned short*)(ws + 16777216);    // 6 MB
    unsigned short* WoT = (unsigned short*)(ws + 23068672);    // 2 MB
    unsigned short* Qb  = (unsigned short*)(ws + 25165824);    // 16 MB
    unsigned short* Kb  = (unsigned short*)(ws + 41943040);    // 16 MB
    unsigned short* Vtb = (unsigned short*)(ws + 58720256);    // 16 MB (transposed)
    unsigned short* ctx = (unsigned short*)(ws + 75497472);    // 16 MB

    convert_x<<<8192, 256, 0, stream>>>(x, xb);
    transpose_w<<<dim3(32, 32, 4), dim3(32, 8), 0, stream>>>(Wq, Wk, Wv, Wo, WT, WoT);
    gemm_bt<0><<<dim3(24, 64), 256, 0, stream>>>(xb, WT, Qb, Kb, Vtb, nullptr, nullptr);
    attn<<<2048, 256, 0, stream>>>(Qb, Kb, Vtb, ctx);
    gemm_bt<1><<<dim3(8, 64), 256, 0, stream>>>(ctx, WoT, nullptr, nullptr, nullptr, bo, out);
}

// Round 6
// 281.705 us; speedup vs baseline: 1.8934x; 1.0517x over previous
//
#include <hip/hip_runtime.h>
#include <hip/hip_bf16.h>
#include <math.h>

// ---------------------------------------------------------------------------
// MultiHeadAttention: x[4,2048,1024] -> causal MHA (16 heads, d=64) -> out proj
// bf16 MFMA everywhere.
// Attention (S^T orientation): S^T = K(A) x Q^T(B) so each lane owns ONE q
// (col=lm) -> scalar softmax state, and S^T's C layout (k=quad*4+r) is exactly
// the B-frag of mfma_16x16x16 -> PV with P register-to-register (no LDS P).
// Double-buffered K/V staging (1 barrier/trip), LPT dispatch, exp2 softmax.
// GEMMs: m97 pattern — global_load_lds width-16 staging, stride-64 LDS.
// ---------------------------------------------------------------------------

typedef __bf16  bf16x8  __attribute__((ext_vector_type(8)));
typedef float   floatx4 __attribute__((ext_vector_type(4)));
typedef short   shortx4 __attribute__((ext_vector_type(4)));

#if __has_builtin(__builtin_amdgcn_mfma_f32_16x16x16bf16_1k)
#define HAVE_MFMA16 1
#endif

__device__ __forceinline__ unsigned short f2bf(float f) {
    __hip_bfloat16 h = __float2bfloat16(f);
    return *reinterpret_cast<unsigned short*>(&h);
}

// async global->LDS, 16 B per lane; LDS dest = wave-uniform base + lane*16
__device__ __forceinline__ void gll16(const unsigned short* g, unsigned short* l) {
    __builtin_amdgcn_global_load_lds(
        (const __attribute__((address_space(1))) unsigned int*)g,
        (__attribute__((address_space(3))) unsigned int*)l, 16, 0, 0);
}

// ---------------------------------------------------------------- convert x
__global__ void convert_x(const float* __restrict__ x, unsigned short* __restrict__ xb) {
    int i = (blockIdx.x * 256 + threadIdx.x) * 4;
    float4 v = *(const float4*)(x + i);
    ushort4 o;
    o.x = f2bf(v.x); o.y = f2bf(v.y); o.z = f2bf(v.z); o.w = f2bf(v.w);
    *(ushort4*)(xb + i) = o;
}

// ------------------------------------------------------- transpose weights
__global__ void transpose_w(const float* __restrict__ Wq, const float* __restrict__ Wk,
                            const float* __restrict__ Wv, const float* __restrict__ Wo,
                            unsigned short* __restrict__ WT, unsigned short* __restrict__ WoT) {
    __shared__ float tile[32][33];
    int mat = blockIdx.z;
    const float* src = (mat == 0) ? Wq : (mat == 1) ? Wk : (mat == 2) ? Wv : Wo;
    unsigned short* dst = (mat < 3) ? WT : WoT;
    int nbase = (mat < 3) ? mat * 1024 : 0;
    int kt = blockIdx.x * 32, nt = blockIdx.y * 32;
    int tx = threadIdx.x, ty = threadIdx.y;
    for (int j = 0; j < 32; j += 8)
        tile[ty + j][tx] = src[(kt + ty + j) * 1024 + nt + tx];
    __syncthreads();
    for (int j = 0; j < 32; j += 8) {
        int n = nt + ty + j;
        dst[(nbase + n) * 1024 + kt + tx] = f2bf(tile[tx][ty + j]);
    }
}

// ---------------------------------------------------------------- GEMM B^T
// C[M,N] = A[M,1024] @ B^T (B stored [N][1024]). 128x128 tile, BK=64.
// m97-style staging: global_load_lds dwordx4, unpadded stride-64 LDS.
template <int EPI>
__global__ __launch_bounds__(256) void gemm_bt(const unsigned short* __restrict__ A,
                                               const unsigned short* __restrict__ B,
                                               unsigned short* __restrict__ Qo,
                                               unsigned short* __restrict__ Ko,
                                               unsigned short* __restrict__ Vo,
                                               const float* __restrict__ bias,
                                               float* __restrict__ Out) {
    __shared__ __align__(16) unsigned short As[128 * 64];
    __shared__ __align__(16) unsigned short Bs[128 * 64];

    int tid = threadIdx.x;
    int lane = tid & 63, w = tid >> 6;
    int wm = w >> 1, wn = w & 1;
    int lm = lane & 15, quad = lane >> 4;
    int m0 = blockIdx.y * 128, n0 = blockIdx.x * 128;

    floatx4 acc[4][4] = {};

    for (int kb = 0; kb < 1024; kb += 64) {
        __syncthreads();
        for (int p = 0; p < 4; ++p) {
            int id = p * 256 + tid;
            int row = id >> 3, cc = (id & 7) * 8;
            int lbase = (p * 256 + w * 64) * 8;  // wave-uniform; HW adds lane*16B
            gll16(&A[(m0 + row) * 1024 + kb + cc], &As[lbase]);
            gll16(&B[(n0 + row) * 1024 + kb + cc], &Bs[lbase]);
        }
        __syncthreads();
        bf16x8 af[2][4], bf[2][4];
        for (int ks = 0; ks < 2; ++ks)
            for (int i = 0; i < 4; ++i) {
                af[ks][i] = *(const bf16x8*)&As[(wm * 64 + i * 16 + lm) * 64 + ks * 32 + quad * 8];
                bf[ks][i] = *(const bf16x8*)&Bs[(wn * 64 + i * 16 + lm) * 64 + ks * 32 + quad * 8];
            }
        for (int mi = 0; mi < 4; ++mi)
            for (int ni = 0; ni < 4; ++ni) {
                acc[mi][ni] = __builtin_amdgcn_mfma_f32_16x16x32_bf16(af[0][mi], bf[0][ni], acc[mi][ni], 0, 0, 0);
                acc[mi][ni] = __builtin_amdgcn_mfma_f32_16x16x32_bf16(af[1][mi], bf[1][ni], acc[mi][ni], 0, 0, 0);
            }
    }

    // C/D layout: col = lane&15, row = quad*4 + r
    for (int mi = 0; mi < 4; ++mi)
        for (int ni = 0; ni < 4; ++ni) {
            int gcol = n0 + wn * 64 + ni * 16 + lm;
            if constexpr (EPI == 0) {
                int which = gcol >> 10, hn = gcol & 1023;
                int h = hn >> 6, d = hn & 63;
                int grow0 = m0 + wm * 64 + mi * 16 + quad * 4;
                int bb = grow0 >> 11, s = grow0 & 2047;
                if (which == 2) {
                    ushort4 pk;
                    pk.x = f2bf(acc[mi][ni][0]); pk.y = f2bf(acc[mi][ni][1]);
                    pk.z = f2bf(acc[mi][ni][2]); pk.w = f2bf(acc[mi][ni][3]);
                    *(ushort4*)&Vo[((size_t)(bb * 16 + h) * 64 + d) * 2048 + s] = pk;
                } else {
                    unsigned short* dst = (which == 0) ? Qo : Ko;
                    for (int r = 0; r < 4; ++r)
                        dst[(((bb * 16 + h) * 2048) + s + r) * 64 + d] = f2bf(acc[mi][ni][r]);
                }
            } else {
                float bv = bias[gcol];
                for (int r = 0; r < 4; ++r) {
                    int grow = m0 + wm * 64 + mi * 16 + quad * 4 + r;
                    Out[(size_t)grow * 1024 + gcol] = acc[mi][ni][r] + bv;
                }
            }
        }
}

// ------------------------------------------------------------- attention
// Flat grid 2048 = (qt heavy-first) x 64 bh. 4 waves x 16 q-rows. KB=64.
// S^T orientation: q = lm (scalar softmax state), k = quad*4+r.
__global__ __launch_bounds__(256) void attn(const unsigned short* __restrict__ Q,
                                            const unsigned short* __restrict__ K,
                                            const unsigned short* __restrict__ Vt,
                                            unsigned short* __restrict__ ctx) {
    constexpr int LKS = 72;
    __shared__ __align__(16) unsigned short Ks[2][64 * LKS];
    __shared__ __align__(16) unsigned short Vts[2][64 * LKS];

    int tid = threadIdx.x, lane = tid & 63, w = tid >> 6;
    int lm = lane & 15, quad = lane >> 4;
    int blk = blockIdx.x;
    int bh = blk & 63;
    int qt = 31 - (blk >> 6);   // LPT: heaviest q-tiles dispatch first
    int trips = qt + 1;
    const unsigned short* Qg  = Q  + (size_t)bh * 2048 * 64;
    const unsigned short* Kg  = K  + (size_t)bh * 2048 * 64;
    const unsigned short* Vtg = Vt + (size_t)bh * 64 * 2048;

    // Q fragment: lane holds Q[q = qt*64+w*16+lm][d = quad*8+j] — used as the
    // B operand of the S^T MFMA (B[k-dim=d][n=q]); same bytes as an A-frag.
    int qrow = qt * 64 + w * 16 + lm;
    bf16x8 aq0 = *(const bf16x8*)&Qg[qrow * 64 + quad * 8];
    bf16x8 aq1 = *(const bf16x8*)&Qg[qrow * 64 + 32 + quad * 8];

    floatx4 O[4] = {};            // O^T: per dblk, lane holds d=quad*4+r, q=lm
    float mrow = -INFINITY, lrow = 0.f;   // scalar per lane (one q per lane)
    const float scl = 0.125f * 1.44269504f;  // 1/sqrt(64) * log2(e)

    int r0 = tid >> 3, c0 = (tid & 7) * 8;  // staging coords

    // prologue: stage tile 0 into buffer 0
    {
        uint4 k0 = *(const uint4*)&Kg[r0 * 64 + c0];
        uint4 k1 = *(const uint4*)&Kg[(r0 + 32) * 64 + c0];
        uint4 v0 = *(const uint4*)&Vtg[r0 * 2048 + c0];
        uint4 v1 = *(const uint4*)&Vtg[(r0 + 32) * 2048 + c0];
        *(uint4*)&Ks[0][r0 * LKS + c0]         = k0;
        *(uint4*)&Ks[0][(r0 + 32) * LKS + c0]  = k1;
        *(uint4*)&Vts[0][r0 * LKS + c0]        = v0;
        *(uint4*)&Vts[0][(r0 + 32) * LKS + c0] = v1;
    }
    __syncthreads();

    for (int t = 0; t < trips; ++t) {
        int cur = t & 1, nxt = cur ^ 1;
        bool pre = (t + 1 < trips);
        uint4 pk0, pk1, pv0, pv1;
        if (pre) {  // issue next tile's loads NOW; they complete under compute
            int kb2 = (t + 1) * 64;
            pk0 = *(const uint4*)&Kg[(kb2 + r0) * 64 + c0];
            pk1 = *(const uint4*)&Kg[(kb2 + r0 + 32) * 64 + c0];
            pv0 = *(const uint4*)&Vtg[r0 * 2048 + kb2 + c0];
            pv1 = *(const uint4*)&Vtg[(r0 + 32) * 2048 + kb2 + c0];
        }

        const unsigned short* Kc = Ks[cur];
        const unsigned short* Vc = Vts[cur];

        // S^T tile n: rows k = n*16+quad*4+r, cols q = lm
        floatx4 s[4];
        for (int n = 0; n < 4; ++n) {
            bf16x8 a0 = *(const bf16x8*)&Kc[(n * 16 + lm) * LKS + quad * 8];
            bf16x8 a1 = *(const bf16x8*)&Kc[(n * 16 + lm) * LKS + 32 + quad * 8];
            floatx4 z = {};
            z = __builtin_amdgcn_mfma_f32_16x16x32_bf16(a0, aq0, z, 0, 0, 0);
            z = __builtin_amdgcn_mfma_f32_16x16x32_bf16(a1, aq1, z, 0, 0, 0);
            s[n] = z;
        }

        // mask + scale (diag tile only), scalar online softmax over this lane's q
        bool diag = (t == trips - 1);  // wave-uniform
        float v[4][4];
        if (diag) {
            int qr = w * 16 + lm;
            for (int n = 0; n < 4; ++n)
                for (int r = 0; r < 4; ++r)
                    v[n][r] = (n * 16 + quad * 4 + r <= qr) ? s[n][r] * scl : -INFINITY;
        } else {
            for (int n = 0; n < 4; ++n)
                for (int r = 0; r < 4; ++r)
                    v[n][r] = s[n][r] * scl;
        }
        float vm = v[0][0];
        for (int n = 0; n < 4; ++n)
            for (int r = 0; r < 4; ++r) vm = fmaxf(vm, v[n][r]);
        vm = fmaxf(vm, __shfl_xor(vm, 16));
        vm = fmaxf(vm, __shfl_xor(vm, 32));
        float mnew = fmaxf(mrow, vm);
        float alpha = __builtin_amdgcn_exp2f(mrow - mnew);
        float p[4][4], rs = 0.f;
        for (int n = 0; n < 4; ++n)
            for (int r = 0; r < 4; ++r) {
                p[n][r] = __builtin_amdgcn_exp2f(v[n][r] - mnew);
                rs += p[n][r];
            }
        rs += __shfl_xor(rs, 16);
        rs += __shfl_xor(rs, 32);
        lrow = lrow * alpha + rs;
        mrow = mnew;
        for (int dblk = 0; dblk < 4; ++dblk) O[dblk] *= alpha;

#ifdef HAVE_MFMA16
        // P^T is ALREADY the 16x16x16 B-frag (B[k=quad*4+i][n=lm]) — no LDS.
        shortx4 pb[4];
        for (int n = 0; n < 4; ++n) {
            shortx4 t4;
            t4[0] = (short)f2bf(p[n][0]); t4[1] = (short)f2bf(p[n][1]);
            t4[2] = (short)f2bf(p[n][2]); t4[3] = (short)f2bf(p[n][3]);
            pb[n] = t4;
        }
        for (int dblk = 0; dblk < 4; ++dblk)
            for (int n = 0; n < 4; ++n) {
                // A-frag: V^T[dblk*16+lm][n*16 + quad*4 + i]
                shortx4 va = *(const shortx4*)&Vc[(dblk * 16 + lm) * LKS + n * 16 + quad * 4];
                O[dblk] = __builtin_amdgcn_mfma_f32_16x16x16bf16_1k(va, pb[n], O[dblk], 0, 0, 0);
            }
#else
        // Fallback: build K=32 B-frags via shfl (dword j from lane lm+q'*16).
        unsigned int dw[4][2];
        for (int n = 0; n < 4; ++n) {
            dw[n][0] = (unsigned int)f2bf(p[n][0]) | ((unsigned int)f2bf(p[n][1]) << 16);
            dw[n][1] = (unsigned int)f2bf(p[n][2]) | ((unsigned int)f2bf(p[n][3]) << 16);
        }
        bool hiTile = (quad >> 1);
        for (int hh = 0; hh < 2; ++hh) {
            unsigned int bp[4];
            for (int j = 0; j < 4; ++j) {
                int srcLane = lm + (((quad & 1) * 2 + (j >> 1)) << 4);
                unsigned int lo = __shfl((int)dw[2 * hh][j & 1], srcLane);
                unsigned int hi = __shfl((int)dw[2 * hh + 1][j & 1], srcLane);
                bp[j] = hiTile ? hi : lo;
            }
            bf16x8 bfrag = *(bf16x8*)bp;
            for (int dblk = 0; dblk < 4; ++dblk) {
                bf16x8 av = *(const bf16x8*)&Vc[(dblk * 16 + lm) * LKS + hh * 32 + quad * 8];
                O[dblk] = __builtin_amdgcn_mfma_f32_16x16x32_bf16(av, bfrag, O[dblk], 0, 0, 0);
            }
        }
#endif

        if (pre) {  // loads completed under compute; write into other buffer
            *(uint4*)&Ks[nxt][r0 * LKS + c0]         = pk0;
            *(uint4*)&Ks[nxt][(r0 + 32) * LKS + c0]  = pk1;
            *(uint4*)&Vts[nxt][r0 * LKS + c0]        = pv0;
            *(uint4*)&Vts[nxt][(r0 + 32) * LKS + c0] = pv1;
        }
        __syncthreads();
    }

    // O^T epilogue: lane owns q=lm, d = dblk*16 + quad*4 + r -> packed stores
    int b = bh >> 4, h = bh & 15;
    int q = qt * 64 + w * 16 + lm;
    float inv = 1.0f / lrow;
    for (int dblk = 0; dblk < 4; ++dblk) {
        ushort4 pk;
        pk.x = f2bf(O[dblk][0] * inv); pk.y = f2bf(O[dblk][1] * inv);
        pk.z = f2bf(O[dblk][2] * inv); pk.w = f2bf(O[dblk][3] * inv);
        *(ushort4*)&ctx[((size_t)(b * 2048 + q)) * 1024 + h * 64 + dblk * 16 + quad * 4] = pk;
    }
}

// ---------------------------------------------------------------- launch
extern "C" void kernel_launch(void* const* d_in, const int* in_sizes, int n_in,
                              void* d_out, int out_size, void* d_ws, size_t ws_size,
                              hipStream_t stream) {
    const float* x   = (const float*)d_in[0];
    const float* Wq  = (const float*)d_in[1];
    const float* Wk  = (const float*)d_in[2];
    const float* Wv  = (const float*)d_in[3];
    const float* Wo  = (const float*)d_in[4];
    const float* bo  = (const float*)d_in[5];
    float* out = (float*)d_out;

    char* ws = (char*)d_ws;
    unsigned short* xb  = (unsigned short*)(ws);               // 16 MB
    unsigned short* WT  = (unsigned short*)(ws + 16777216);    // 6 MB
    unsigned short* WoT = (unsigned short*)(ws + 23068672);    // 2 MB
    unsigned short* Qb  = (unsigned short*)(ws + 25165824);    // 16 MB
    unsigned short* Kb  = (unsigned short*)(ws + 41943040);    // 16 MB
    unsigned short* Vtb = (unsigned short*)(ws + 58720256);    // 16 MB (transposed)
    unsigned short* ctx = (unsigned short*)(ws + 75497472);    // 16 MB

    convert_x<<<8192, 256, 0, stream>>>(x, xb);
    transpose_w<<<dim3(32, 32, 4), dim3(32, 8), 0, stream>>>(Wq, Wk, Wv, Wo, WT, WoT);
    gemm_bt<0><<<dim3(24, 64), 256, 0, stream>>>(xb, WT, Qb, Kb, Vtb, nullptr, nullptr);
    attn<<<2048, 256, 0, stream>>>(Qb, Kb, Vtb, ctx);
    gemm_bt<1><<<dim3(8, 64), 256, 0, stream>>>(ctx, WoT, nullptr, nullptr, nullptr, bo, out);
}